// Round 8
// baseline (90.702 us; speedup 1.0000x reference)
//
#include <hip/hip_runtime.h>

#define H 1024
#define N 64
#define L 2048
#define TPB 256
#define KK 4              // l-positions per thread; 2 blocks per h
#define NBLK (H * 2)
#define REP 2             // DIAGNOSTIC: run phase 2 twice, store acc*0.5 (exact)

#define INV2PI 0.15915494309189535f

typedef float f32x2 __attribute__((ext_vector_type(2)));

// complex multiply r = w * s, layout (re, im) = (lo, hi). Verified R1-R6.
// t = (w.re*s.re, w.im*s.re); r = (t.lo - w.im*s.im, t.hi + w.re*s.im)
__device__ __forceinline__ f32x2 cmul(f32x2 w, f32x2 s) {
    f32x2 t, r;
    asm("v_pk_mul_f32 %0, %1, %2 op_sel_hi:[1,0]"
        : "=v"(t) : "v"(w), "v"(s));
    asm("v_pk_fma_f32 %0, %1, %2, %3 op_sel:[1,1,0] op_sel_hi:[0,1,1] neg_lo:[1,0,0]"
        : "=v"(r) : "v"(w), "v"(s), "v"(t));
    return r;
}

__device__ __forceinline__ f32x2 cexp_rev(float mag_arg, float rev_arg) {
    float m = __expf(mag_arg);
    float rv = rev_arg - floorf(rev_arg);
    f32x2 e;
    e.x = m * __builtin_amdgcn_cosf(rv);
    e.y = m * __builtin_amdgcn_sinf(rv);
    return e;
}

// Identical structure to round 6 (2 blocks/h, KK=4, LDS tables), except phase 2
// executes REP times (syncthreads between reps prevents cross-rep CSE/LICM of
// the LDS loads and dependent asm chain) and the store scales by 1/REP (exact
// power of 2). Purpose: lift kernel duration above the harness poison-fill
// floor (~40 us) so it surfaces in the top-5 rocprof rows WITH counters.
__global__ __launch_bounds__(TPB, 8) void s4d_fused(const float* __restrict__ log_dt,
                                                    const float* __restrict__ Cv,
                                                    const float* __restrict__ Av,
                                                    float* __restrict__ out)
{
    __shared__ f32x2 W16[N][16];   // 8 KB
    __shared__ f32x2 E1t[N][16];   // 8 KB
    __shared__ f32x2 Sv[N];        // 512 B

    const int b    = blockIdx.x;
    const int h    = b >> 1;
    const int half = b & 1;
    const int t    = threadIdx.x;

    // ---------- phase 1: tables ----------
    {
        const int n  = t >> 2;          // 4 threads per n
        const int j0 = (t & 3) << 2;    // each computes 4 j's
        float dt = __expf(log_dt[h]);

        float2 a2 = ((const float2*)Av)[n];
        float dr    = dt * a2.x;
        float direv = dt * a2.y * INV2PI;

        f32x2 r1 = cexp_rev(dr, direv);
        float2 c2 = ((const float2*)Cv)[h * N + n];
        float er = r1.x - 1.0f, ei = r1.y;
        float tr = c2.x * er - c2.y * ei;
        float ti = c2.x * ei + c2.y * er;
        float inv = 2.0f / (a2.x * a2.x + a2.y * a2.y);
        f32x2 cm;
        cm.x = (tr * a2.x + ti * a2.y) * inv;
        cm.y = (ti * a2.x - tr * a2.y) * inv;

        const float off = (float)(half << 10);   // 0 or 1024
#pragma unroll
        for (int jj = 0; jj < 4; ++jj) {
            float fj = (float)(j0 + jj);
            E1t[n][j0 + jj] = cexp_rev(dr * fj, direv * fj);
            float fg = fj * 16.0f + off;
            W16[n][j0 + jj] = cmul(cexp_rev(dr * fg, direv * fg), cm);
        }

        if (t < N) {
            float2 a2b = ((const float2*)Av)[t];
            float drb = dt * a2b.x;
            float dib = dt * a2b.y * INV2PI;
            Sv[t] = cexp_rev(drb * 256.0f, dib * 256.0f);
        }
    }

    // ---------- phase 2 (x REP): trans-free recurrence ----------
    float acc[KK];
#pragma unroll
    for (int k = 0; k < KK; ++k) acc[k] = 0.0f;

    const int jhi = t >> 4;
    const int jlo = t & 15;

#pragma unroll 1
    for (int rep = 0; rep < REP; ++rep) {
        __syncthreads();   // memory fence: forces LDS reloads each rep (no CSE)

#pragma unroll 2
        for (int n = 0; n < N; ++n) {
            f32x2 w16 = W16[n][jhi];
            f32x2 e1  = E1t[n][jlo];
            f32x2 s   = Sv[n];
            f32x2 w = cmul(e1, w16);   // w0 = cm * exp(dtA * l0)

#pragma unroll
            for (int k = 0; k < KK; ++k) {
                acc[k] += w.x;         // scalar re-accumulate only
                w = cmul(w, s);
            }
        }
    }

    const float scale = 1.0f / (float)REP;   // exact (power of 2)
    float* o = out + h * L + (half << 10) + t;
#pragma unroll
    for (int k = 0; k < KK; ++k) o[k * TPB] = acc[k] * scale;
}

extern "C" void kernel_launch(void* const* d_in, const int* in_sizes, int n_in,
                              void* d_out, int out_size, void* d_ws, size_t ws_size,
                              hipStream_t stream) {
    const float* log_dt = (const float*)d_in[0];
    const float* Cv     = (const float*)d_in[1];   // (H, N, 2)
    const float* Av     = (const float*)d_in[2];   // (N, 2)
    float* out          = (float*)d_out;           // (H, L) fp32

    s4d_fused<<<NBLK, TPB, 0, stream>>>(log_dt, Cv, Av, out);
}

// Round 9
// 77.686 us; speedup vs baseline: 1.1675x; 1.1675x over previous
//
#include <hip/hip_runtime.h>

#define H 1024
#define N 64
#define L 2048
#define TPB 256
#define HALF_L 1024
#define NBLK (H * 2)      // 2 blocks per h, each covers 1024 l-positions
#define KPT 16            // l-positions per thread (stride 64 within the half)
#define NPW 16            // n's per wave (4 waves x 16 = 64)

#define INV2PI 0.15915494309189535f

typedef float f32x2 __attribute__((ext_vector_type(2)));

// complex multiply r = w * s, layout (re, im) = (lo, hi). Verified R1-R8.
__device__ __forceinline__ f32x2 cmul(f32x2 w, f32x2 s) {
    f32x2 t, r;
    asm("v_pk_mul_f32 %0, %1, %2 op_sel_hi:[1,0]"
        : "=v"(t) : "v"(w), "v"(s));
    asm("v_pk_fma_f32 %0, %1, %2, %3 op_sel:[1,1,0] op_sel_hi:[0,1,1] neg_lo:[1,0,0]"
        : "=v"(r) : "v"(w), "v"(s), "v"(t));
    return r;
}

__device__ __forceinline__ f32x2 cexp_rev(float mag_arg, float rev_arg) {
    float m = __expf(mag_arg);
    float rv = rev_arg - floorf(rev_arg);
    f32x2 e;
    e.x = m * __builtin_amdgcn_cosf(rv);
    e.y = m * __builtin_amdgcn_sinf(rv);
    return e;
}

// Block b covers h = b>>1, l in [1024*(b&1), 1024*(b&1)+1024).
// Wave w (of 4) handles n in [16w, 16w+16); lane j owns l = j + 64k, k<16.
// Tables: W4[n][jhi] = cm * exp(dtA*(16*jhi + 1024*half)); E1[n][jlo] = exp(dtA*jlo);
//         CF[n] = (s.re, s.im, 2*s.re, -|s|^2) with s = exp(dtA*64).
// Phase 2 per (n, lane): w0 = W4*E1 (complex); u0 = Re(w0), u1 = Re(w0*s);
// then u_k = 2a*u_{k-1} - |s|^2*u_{k-2}  (real 2nd-order recurrence, 3 instrs/term).
// Cross-wave n-sum via LDS partials overlaid on the dead tables.
__global__ __launch_bounds__(TPB, 8) void s4d_fused(const float* __restrict__ log_dt,
                                                    const float* __restrict__ Cv,
                                                    const float* __restrict__ Av,
                                                    float* __restrict__ out)
{
    __shared__ __align__(16) char smem[16384];   // 16 KB: tables (11 KB) then partials
    float4* CF = (float4*)smem;                  // [N]      1 KB
    f32x2*  W4 = (f32x2*)(smem + 1024);          // [N][4]   2 KB
    f32x2*  E1 = (f32x2*)(smem + 3072);          // [N][16]  8 KB

    const int b    = blockIdx.x;
    const int h    = b >> 1;
    const int half = b & 1;
    const int t    = threadIdx.x;

    // ---------- phase 1: tables (4 threads per n) ----------
    {
        const int n = t >> 2;
        const int q = t & 3;
        float dt = __expf(log_dt[h]);

        float2 a2 = ((const float2*)Av)[n];
        float dr    = dt * a2.x;
        float direv = dt * a2.y * INV2PI;    // phase in revolutions per l

        // cm = 2 * C * (exp(dtA) - 1) / A
        f32x2 r1 = cexp_rev(dr, direv);
        float2 c2 = ((const float2*)Cv)[h * N + n];
        float er = r1.x - 1.0f, ei = r1.y;
        float tr = c2.x * er - c2.y * ei;
        float ti = c2.x * ei + c2.y * er;
        float inv = 2.0f / (a2.x * a2.x + a2.y * a2.y);
        f32x2 cm;
        cm.x = (tr * a2.x + ti * a2.y) * inv;
        cm.y = (ti * a2.x - tr * a2.y) * inv;

        // E1: 4 entries each
#pragma unroll
        for (int jj = 0; jj < 4; ++jj) {
            float fj = (float)(q * 4 + jj);
            E1[n * 16 + q * 4 + jj] = cexp_rev(dr * fj, direv * fj);
        }
        // W4: one entry each (includes half-offset and cm)
        float fg = 16.0f * (float)q + 1024.0f * (float)half;
        W4[n * 4 + q] = cmul(cexp_rev(dr * fg, direv * fg), cm);
        // CF: one thread per n
        if (q == 0) {
            f32x2 s = cexp_rev(dr * 64.0f, direv * 64.0f);
            CF[n] = make_float4(s.x, s.y, 2.0f * s.x, -(s.x * s.x + s.y * s.y));
        }
    }
    __syncthreads();

    // ---------- phase 2: real-recurrence over this wave's 16 n's ----------
    const int w   = t >> 6;        // wave id 0..3
    const int j   = t & 63;        // lane
    const int jhi = j >> 4;
    const int jlo = j & 15;
    const int n0  = w * NPW;

    float acc[KPT];
#pragma unroll
    for (int k = 0; k < KPT; ++k) acc[k] = 0.0f;

#pragma unroll 2
    for (int ni = 0; ni < NPW; ++ni) {
        const int n = n0 + ni;
        f32x2 w4  = W4[n * 4 + jhi];     // 4 distinct per wave
        f32x2 e1  = E1[n * 16 + jlo];    // 16 distinct, 8B each: conflict-free
        float4 cf = CF[n];               // wave-uniform broadcast

        f32x2 w0 = cmul(e1, w4);         // cm * exp(dtA * l0), l0 = 16jhi+jlo+1024*half
        float u0 = w0.x, v0 = w0.y;
        float u1 = u0 * cf.x - v0 * cf.y;   // Re(w0 * s)
        acc[0] += u0;
        acc[1] += u1;
#pragma unroll
        for (int k = 2; k < KPT; ++k) {
            float u2 = cf.z * u1 + cf.w * u0;   // 2a*u1 - |s|^2*u0
            acc[k] += u2;
            u0 = u1; u1 = u2;
        }
    }
    __syncthreads();    // all waves done reading tables -> safe to overlay

    // ---------- cross-wave reduce via LDS partials ----------
    float* part = (float*)smem;          // [4][1024] f32 = 16 KB
#pragma unroll
    for (int k = 0; k < KPT; ++k)
        part[w * HALF_L + j + 64 * k] = acc[k];   // 2 lanes/bank: free
    __syncthreads();

    float* o = out + h * L + (half << 10);
#pragma unroll
    for (int k2 = 0; k2 < 4; ++k2) {
        int l = t + 256 * k2;
        o[l] = part[l] + part[HALF_L + l] + part[2 * HALF_L + l] + part[3 * HALF_L + l];
    }
}

extern "C" void kernel_launch(void* const* d_in, const int* in_sizes, int n_in,
                              void* d_out, int out_size, void* d_ws, size_t ws_size,
                              hipStream_t stream) {
    const float* log_dt = (const float*)d_in[0];
    const float* Cv     = (const float*)d_in[1];   // (H, N, 2)
    const float* Av     = (const float*)d_in[2];   // (N, 2)
    float* out          = (float*)d_out;           // (H, L) fp32

    s4d_fused<<<NBLK, TPB, 0, stream>>>(log_dt, Cv, Av, out);
}